// Round 8
// baseline (2904.940 us; speedup 1.0000x reference)
//
#include <hip/hip_runtime.h>

#define D_DIM 2048
#define E_DIM 64
#define BT 128                  // tokens per block
#define DSPLIT 2
#define DCH (D_DIM / DSPLIT)    // 1024 floats per block
#define DK 128                  // floats per tile per token row (512 B contiguous!)
#define NTILE (DCH / DK)        // 8
#define XB (BT * DK * 4)        // 65536 B per buffer
#define NWIN (DCH / 8)          // 128 8-d W windows per block

typedef __attribute__((address_space(3))) char as3_char;
typedef __attribute__((address_space(1))) const char as1_char;

// Block (bx,by): tokens [bx*128,+128) x all 64 experts over d-chunk [by*1024,+1024).
// KEY CHANGE vs R3-R7: every global_load_lds instruction now fetches TWO COMPLETE
// 512-B token-row segments (previous designs fetched 16x 64-B segments 8 KB apart
// -> HBM delivered only ~850 GB/s in all four variants; that granularity was the
// invariant bottleneck). W stays in VGPRs, loads fully wave-uniform.
__global__ __launch_bounds__(512, 2) void router_gemm(
    const float* __restrict__ x, const float* __restrict__ wgt,
    float* __restrict__ out, int N) {
  __shared__ __align__(16) char lds[2][XB];
  const int tid = threadIdx.x;
  const int l = tid & 63;
  const int wv = tid >> 6;  // 0..7
  const int tbase = blockIdx.x * BT;
  const int dbase = blockIdx.y * DCH;

  // ---- staging: linear LDS dest (row stride 512 B = 32 chunks of 16 B);
  // stored[r][c] = global[r][c ^ (r&31)] (both-sides XOR involution).
  // Instr q of wave wv covers rows 16wv+2q, +1. Lane l -> row += l>>5,
  // stored chunk = l&31, so source chunk = (l&31) ^ ((16wv+2q)&31 | (l>>5)).
  const float* xsrc[8];
#pragma unroll
  for (int q = 0; q < 8; ++q) {
    int r2 = 16 * wv + 2 * q;
    int row = r2 + (l >> 5);
    int sch = (l & 31) ^ ((r2 & 31) | (l >> 5));
    xsrc[q] = x + (size_t)(tbase + row) * D_DIM + dbase + 4 * sch;
  }

  auto STAGE = [&](int b, int t) {
    const int d0 = t * DK;
#pragma unroll
    for (int q = 0; q < 8; ++q)
      __builtin_amdgcn_global_load_lds(
          (as1_char*)(const char*)(xsrc[q] + d0),
          (as3_char*)&lds[b][(wv * 8 + q) * 1024], 16, 0, 0);
  };

  // ---- compute mapping: lane l owns tokens {l, l+64}; wave owns experts
  // wv*8..+8 (wave-uniform -> W loads are broadcast, 1 line per instr).
  const int w8 = wv * 8;
  const int xbase0 = l * 512 + ((l & 31) << 4);
  const int xbase1 = (l + 64) * 512 + ((l & 31) << 4);

  const float* wpj[8];
#pragma unroll
  for (int j = 0; j < 8; ++j)
    wpj[j] = wgt + (size_t)(w8 + j) * D_DIM + dbase;

  float acc[2][8];
#pragma unroll
  for (int i = 0; i < 2; ++i)
#pragma unroll
    for (int j = 0; j < 8; ++j) acc[i][j] = 0.f;

  float4 wA[8][2], wB[8][2];  // [expert][chunk-in-8d-window]

#define LOADW(DST, g)                                        \
  {                                                          \
    _Pragma("unroll") for (int j = 0; j < 8; ++j) {          \
      DST[j][0] = *(const float4*)(wpj[j] + (g) * 8);        \
      DST[j][1] = *(const float4*)(wpj[j] + (g) * 8 + 4);    \
    }                                                        \
  }

#define COMPUTE(W, c0)                                                   \
  {                                                                      \
    float4 x0a = *(const float4*)(buf + (xbase0 ^ ((c0) << 4)));         \
    float4 x1a = *(const float4*)(buf + (xbase1 ^ ((c0) << 4)));         \
    float4 x0b = *(const float4*)(buf + (xbase0 ^ (((c0) + 1) << 4)));   \
    float4 x1b = *(const float4*)(buf + (xbase1 ^ (((c0) + 1) << 4)));   \
    _Pragma("unroll") for (int j = 0; j < 8; ++j) {                      \
      acc[0][j] = fmaf(x0a.x, W[j][0].x, acc[0][j]);                     \
      acc[0][j] = fmaf(x0a.y, W[j][0].y, acc[0][j]);                     \
      acc[0][j] = fmaf(x0a.z, W[j][0].z, acc[0][j]);                     \
      acc[0][j] = fmaf(x0a.w, W[j][0].w, acc[0][j]);                     \
      acc[0][j] = fmaf(x0b.x, W[j][1].x, acc[0][j]);                     \
      acc[0][j] = fmaf(x0b.y, W[j][1].y, acc[0][j]);                     \
      acc[0][j] = fmaf(x0b.z, W[j][1].z, acc[0][j]);                     \
      acc[0][j] = fmaf(x0b.w, W[j][1].w, acc[0][j]);                     \
      acc[1][j] = fmaf(x1a.x, W[j][0].x, acc[1][j]);                     \
      acc[1][j] = fmaf(x1a.y, W[j][0].y, acc[1][j]);                     \
      acc[1][j] = fmaf(x1a.z, W[j][0].z, acc[1][j]);                     \
      acc[1][j] = fmaf(x1a.w, W[j][0].w, acc[1][j]);                     \
      acc[1][j] = fmaf(x1b.x, W[j][1].x, acc[1][j]);                     \
      acc[1][j] = fmaf(x1b.y, W[j][1].y, acc[1][j]);                     \
      acc[1][j] = fmaf(x1b.z, W[j][1].z, acc[1][j]);                     \
      acc[1][j] = fmaf(x1b.w, W[j][1].w, acc[1][j]);                     \
    }                                                                    \
  }

  // prologue
  STAGE(0, 0);
  LOADW(wA, 0);

  int cur = 0;
  for (int t = 0; t < NTILE; ++t) {
    // Only stage(t) (+ nearly-retired W loads) outstanding here: vmcnt(0) is
    // effectively counted. Raw barrier (no implicit full drain via syncthreads).
    asm volatile("s_waitcnt vmcnt(0)" ::: "memory");
    __builtin_amdgcn_s_barrier();
    __builtin_amdgcn_sched_barrier(0);
    if (t + 1 < NTILE) STAGE(cur ^ 1, t + 1);  // overlaps with this tile's FMAs

    const char* buf = lds[cur];
#pragma unroll
    for (int sw2 = 0; sw2 < 8; ++sw2) {
      const int g = t * 16 + sw2 * 2;
      LOADW(wB, g + 1);           // next 8-d window (always < NWIN)
      COMPUTE(wA, 4 * sw2);       // chunks 4sw2, 4sw2+1
      if (g + 2 < NWIN) LOADW(wA, g + 2);
      COMPUTE(wB, 4 * sw2 + 2);   // chunks 4sw2+2, 4sw2+3
    }
    cur ^= 1;
  }

  // partial store: region = blockIdx.y (disp/comb slots hold partials)
  float* part = out + (size_t)blockIdx.y * ((size_t)N * E_DIM);
  size_t o0 = (size_t)(tbase + l) * E_DIM + w8;
  size_t o1 = (size_t)(tbase + l + 64) * E_DIM + w8;
  *(float4*)(part + o0) = make_float4(acc[0][0], acc[0][1], acc[0][2], acc[0][3]);
  *(float4*)(part + o0 + 4) = make_float4(acc[0][4], acc[0][5], acc[0][6], acc[0][7]);
  *(float4*)(part + o1) = make_float4(acc[1][0], acc[1][1], acc[1][2], acc[1][3]);
  *(float4*)(part + o1 + 4) = make_float4(acc[1][4], acc[1][5], acc[1][6], acc[1][7]);
#undef LOADW
#undef COMPUTE
}

__global__ __launch_bounds__(256) void postprocess(float* out, float* ws, int N) {
  const int lane = threadIdx.x & 63;
  const int wv = threadIdx.x >> 6;
  const size_t NE = (size_t)N * E_DIM;
  float* disp = out;               // holds partial 0 on entry
  float* comb = out + NE;          // holds partial 1 on entry
  float* logits_o = out + 2 * NE;
  float* probs_o = out + 3 * NE;
  float* idx_o = out + 4 * NE + 1;
  float* pn_o = out + 4 * NE + 1 + 2 * (size_t)N;

  float expsum = 0.f;  // per-lane (= per-expert) prob sum over this wave's tokens
  const int t0 = blockIdx.x * 64 + wv * 16;
  for (int k = 0; k < 16; ++k) {
    const size_t t = (size_t)(t0 + k);
    const size_t o = t * E_DIM + lane;
    float lv = disp[o] + comb[o];
    logits_o[o] = lv;
    float m = lv;
#pragma unroll
    for (int off = 32; off; off >>= 1) m = fmaxf(m, __shfl_xor(m, off));
    float p = __expf(lv - m);
    float s = p;
#pragma unroll
    for (int off = 32; off; off >>= 1) s += __shfl_xor(s, off);
    float prob = p / s;
    probs_o[o] = prob;
    expsum += prob;

    // packed key: prob bits | (63-lane) -> lowest index wins ties (jax top_k)
    unsigned long long key =
        ((unsigned long long)__float_as_uint(prob) << 32) | (unsigned)(63 - lane);
    unsigned long long k1 = key;
#pragma unroll
    for (int off = 32; off; off >>= 1) {
      unsigned long long v = __shfl_xor(k1, off);
      if (v > k1) k1 = v;
    }
    int i1 = 63 - (int)(k1 & 63);
    unsigned long long k2 = (lane == i1) ? 0ull : key;
#pragma unroll
    for (int off = 32; off; off >>= 1) {
      unsigned long long v = __shfl_xor(k2, off);
      if (v > k2) k2 = v;
    }
    int i2 = 63 - (int)(k2 & 63);
    float p1 = __uint_as_float((unsigned)(k1 >> 32));
    float p2 = __uint_as_float((unsigned)(k2 >> 32));
    float inv = 1.0f / (p1 + p2);
    float pn1 = p1 * inv, pn2 = p2 * inv;
    float dval = (lane == i1) ? pn1 : ((lane == i2) ? pn2 : 0.f);
    disp[o] = dval;
    comb[o] = dval;
    if (lane == 0) {
      idx_o[2 * t] = (float)i1;
      idx_o[2 * t + 1] = (float)i2;
      pn_o[2 * t] = pn1;
      pn_o[2 * t + 1] = pn2;
    }
  }

  __shared__ float aux_s[4][64];
  aux_s[wv][lane] = expsum;
  __syncthreads();
  if (threadIdx.x < 64) {
    float s = aux_s[0][threadIdx.x] + aux_s[1][threadIdx.x] +
              aux_s[2][threadIdx.x] + aux_s[3][threadIdx.x];
    ws[(size_t)blockIdx.x * 64 + threadIdx.x] = s;  // per-block expert partials
  }
}

__global__ __launch_bounds__(256) void finalize_aux(const float* __restrict__ ws,
                                                    float* __restrict__ auxp,
                                                    int nblocks, int N) {
  __shared__ float red[256];
  const int e = threadIdx.x & 63;
  const int part = threadIdx.x >> 6;
  float s = 0.f;
  for (int b = part; b < nblocks; b += 4) s += ws[(size_t)b * 64 + e];
  red[threadIdx.x] = s;
  __syncthreads();
  if (threadIdx.x < 64) {
    float tot = red[e] + red[64 + e] + red[128 + e] + red[192 + e];
    float pb = tot / (float)N;
    float v = pb * pb;  // aux = mean_e(E*pb^2) = sum_e pb^2
#pragma unroll
    for (int off = 32; off; off >>= 1) v += __shfl_xor(v, off);
    if (threadIdx.x == 0) *auxp = v;
  }
}

extern "C" void kernel_launch(void* const* d_in, const int* in_sizes, int n_in,
                              void* d_out, int out_size, void* d_ws, size_t ws_size,
                              hipStream_t stream) {
  (void)n_in; (void)out_size; (void)ws_size;
  const float* x = (const float*)d_in[0];
  const float* w = (const float*)d_in[1];
  float* out = (float*)d_out;
  const int N = in_sizes[0] / D_DIM;  // 16384
  const int npb = N / 64;             // postprocess blocks (256)

  dim3 gg(N / BT, DSPLIT);  // 128 x 2 = 256 blocks (1 per CU)
  router_gemm<<<gg, dim3(512), 0, stream>>>(x, w, out, N);
  postprocess<<<dim3(npb), dim3(256), 0, stream>>>(out, (float*)d_ws, N);
  finalize_aux<<<dim3(1), dim3(256), 0, stream>>>((const float*)d_ws,
                                                  out + 4 * (size_t)N * E_DIM,
                                                  npb, N);
}